// Round 5
// baseline (151.435 us; speedup 1.0000x reference)
//
#include <hip/hip_runtime.h>
#include <cstdint>
#include <cstddef>

// Shapes: b=2, n=512, m=256, d=32, t=128, ORDER=2, C_OUT=64. All I/O fp32.
// Pipeline:
//   k_adj : adj fp32 -> bf16 [4][256][512]; block 512 also builds
//           Wb[3][64][32] = bf16{W1+W2+W3, W2, W3} from W[64][96]
//   k_g   : gt[b][j][n] = bf16(fc[b][n][j] * (1-mask[b][t][n])), j=d*128+t<4096
//           gt[b][4096+t][n] = bf16(1-mask[b][t][n])   (s-channels)
//   k_ft  : ftT[b][m][t][d] = bf16(ft[b][m][d][t])     (MFMA B-operand layout)
//   k_gemm: MFMA 128x128 tile: for jt<32 (d=jt): ut[bi][m][t][d] = bf16(sum_n adj*g)
//           jt==32: s[bi][m][t]
//   k_mlp : y = relu(bias + Wsum@ftT + r0*(W2@u0T) + r1*(W3@u1T)), r=1/(s+1)
//           pure-MFMA, no LDS, K=32 per GEMM.

using shortx8 = __attribute__((ext_vector_type(8))) short;
using floatx4 = __attribute__((ext_vector_type(4))) float;

__device__ __forceinline__ float b2f(unsigned short u) {
    union { unsigned int i; float f; } v; v.i = ((unsigned int)u) << 16; return v.f;
}
__device__ __forceinline__ unsigned short f2b(float f) {
    union { float f; unsigned int i; } v; v.f = f;
    unsigned int x = v.i;
    return (unsigned short)((x + 0x7FFFu + ((x >> 16) & 1u)) >> 16); // RNE
}
__device__ __forceinline__ void gl_lds16(const unsigned short* g, unsigned short* l) {
    __builtin_amdgcn_global_load_lds(
        (const __attribute__((address_space(1))) unsigned int*)g,
        (__attribute__((address_space(3))) unsigned int*)l, 16, 0, 0);
}

// ---------- adj fp32 -> bf16, plus W-prep in block 512 ----------
__global__ void k_adj(const float* __restrict__ adj, const float* __restrict__ W,
                      unsigned short* __restrict__ adjb, unsigned short* __restrict__ Wb) {
    if (blockIdx.x == 512) {
        for (int e = threadIdx.x; e < 2048; e += 256) {
            int o = e >> 5, d = e & 31;
            float w1 = W[o * 96 + d], w2 = W[o * 96 + 32 + d], w3 = W[o * 96 + 64 + d];
            Wb[e]        = f2b(w1 + w2 + w3);
            Wb[2048 + e] = f2b(w2);
            Wb[4096 + e] = f2b(w3);
        }
        return;
    }
    int i4 = (blockIdx.x * 256 + threadIdx.x) * 4;
    float4 v = *(const float4*)(adj + i4);
    ushort4 o;
    o.x = f2b(v.x); o.y = f2b(v.y); o.z = f2b(v.z); o.w = f2b(v.w);
    *(ushort4*)(adjb + i4) = o;
}

// ---------- build gt[b][j][n] (transposed, bf16, with s-channels) ----------
__global__ void k_g(const float* __restrict__ fc, const float* __restrict__ mask,
                    unsigned short* __restrict__ gt) {
    const int jb = blockIdx.x, nb = blockIdx.y, b = blockIdx.z;
    const int tid = threadIdx.x;
    const int n0 = nb * 32;
    const int r = tid >> 3, c4 = (tid & 7) * 4;
    if (jb >= 128) {
        const int t0 = (jb - 128) * 32;
        float4 mv = *(const float4*)(mask + ((size_t)b * 128 + t0 + r) * 512 + n0 + c4);
        ushort4 o;
        o.x = f2b(1.f - mv.x); o.y = f2b(1.f - mv.y);
        o.z = f2b(1.f - mv.z); o.w = f2b(1.f - mv.w);
        *(ushort4*)(gt + ((size_t)b * 4224 + 4096 + t0 + r) * 512 + n0 + c4) = o;
        return;
    }
    const int j0 = jb * 32;
    const int t0 = j0 & 127;
    __shared__ float wls[32][33];
    __shared__ unsigned short tls[32][34];
    {
        float4 mv = *(const float4*)(mask + ((size_t)b * 128 + t0 + r) * 512 + n0 + c4);
        wls[r][c4 + 0] = 1.f - mv.x; wls[r][c4 + 1] = 1.f - mv.y;
        wls[r][c4 + 2] = 1.f - mv.z; wls[r][c4 + 3] = 1.f - mv.w;
    }
    float4 fv = *(const float4*)(fc + ((size_t)b * 512 + n0 + r) * 4096 + j0 + c4);
    __syncthreads();
    tls[c4 + 0][r] = f2b(fv.x * wls[c4 + 0][r]);
    tls[c4 + 1][r] = f2b(fv.y * wls[c4 + 1][r]);
    tls[c4 + 2][r] = f2b(fv.z * wls[c4 + 2][r]);
    tls[c4 + 3][r] = f2b(fv.w * wls[c4 + 3][r]);
    __syncthreads();
    ushort4 o;
    o.x = tls[r][c4 + 0]; o.y = tls[r][c4 + 1];
    o.z = tls[r][c4 + 2]; o.w = tls[r][c4 + 3];
    *(ushort4*)(gt + ((size_t)b * 4224 + j0 + r) * 512 + n0 + c4) = o;
}

// ---------- ftT[b][m][t][d] = bf16(ft[b][m][d][t]) ----------
__global__ void k_ft(const float* __restrict__ ft, unsigned short* __restrict__ ftT) {
    const int m = blockIdx.x, b = blockIdx.y;
    const int tid = threadIdx.x;
    __shared__ unsigned short l[32][136];
    const float* src = ft + ((size_t)(b * 256 + m) * 32) * 128;
    {
        const int d = tid >> 3, t0 = (tid & 7) * 16;
        float4 v0 = *(const float4*)(src + (size_t)d * 128 + t0);
        float4 v1 = *(const float4*)(src + (size_t)d * 128 + t0 + 4);
        float4 v2 = *(const float4*)(src + (size_t)d * 128 + t0 + 8);
        float4 v3 = *(const float4*)(src + (size_t)d * 128 + t0 + 12);
        unsigned short* p = &l[d][t0];
        p[0]  = f2b(v0.x); p[1]  = f2b(v0.y); p[2]  = f2b(v0.z); p[3]  = f2b(v0.w);
        p[4]  = f2b(v1.x); p[5]  = f2b(v1.y); p[6]  = f2b(v1.z); p[7]  = f2b(v1.w);
        p[8]  = f2b(v2.x); p[9]  = f2b(v2.y); p[10] = f2b(v2.z); p[11] = f2b(v2.w);
        p[12] = f2b(v3.x); p[13] = f2b(v3.y); p[14] = f2b(v3.z); p[15] = f2b(v3.w);
    }
    __syncthreads();
    {
        const int t = tid & 127, dh = (tid >> 7) * 16;
        unsigned short tmp[16];
        #pragma unroll
        for (int k = 0; k < 16; ++k) tmp[k] = l[dh + k][t];
        unsigned short* dst = ftT + ((size_t)(b * 256 + m) * 128 + t) * 32 + dh;
        *(shortx8*)(dst)     = *(const shortx8*)(tmp);
        *(shortx8*)(dst + 8) = *(const shortx8*)(tmp + 8);
    }
}

// ---------- MFMA GEMM: ut[bi][m][t][d] / s[bi][m][t] ----------
// grid (33, 2, 4): jt (128-wide j = one d-channel per tile; jt==32 -> s), mt, bi.
__launch_bounds__(256, 1)
__global__ void k_gemm(const unsigned short* __restrict__ adjb,
                       const unsigned short* __restrict__ gt,
                       unsigned short* __restrict__ ut,
                       unsigned short* __restrict__ sbuf) {
    const int jt = blockIdx.x, mt = blockIdx.y, bi = blockIdx.z;
    const int b = bi >> 1;
    const int tid = threadIdx.x;
    const int wave = tid >> 6, lane = tid & 63;
    const int l15 = lane & 15, quad = lane >> 4;
    const int wm = wave >> 1, wj = wave & 1;

    __shared__ __align__(16) unsigned short Al[128 * 32];
    __shared__ __align__(16) unsigned short Bl[128 * 32];

    const int srow = lane >> 2;
    const int skq  = (lane & 3) * 8;
    const unsigned short* Ag = adjb + ((size_t)bi * 256 + mt * 128) * 512;
    const unsigned short* Bg = gt   + ((size_t)b * 4224 + jt * 128) * 512;

    floatx4 acc[4][4];
    #pragma unroll
    for (int i = 0; i < 4; ++i)
        #pragma unroll
        for (int j = 0; j < 4; ++j) acc[i][j] = (floatx4){0.f, 0.f, 0.f, 0.f};

    for (int k0 = 0; k0 < 512; k0 += 32) {
        __syncthreads();
        #pragma unroll
        for (int r = 0; r < 2; ++r) {
            const int ch = wave * 2 + r;
            const int row = ch * 16 + srow;
            gl_lds16(Ag + (size_t)row * 512 + k0 + skq, &Al[ch * 512]);
            gl_lds16(Bg + (size_t)row * 512 + k0 + skq, &Bl[ch * 512]);
        }
        __syncthreads();

        shortx8 af[4], bf[4];
        #pragma unroll
        for (int i = 0; i < 4; ++i)
            af[i] = *(const shortx8*)&Al[(wm * 64 + i * 16 + l15) * 32 + quad * 8];
        #pragma unroll
        for (int j = 0; j < 4; ++j)
            bf[j] = *(const shortx8*)&Bl[(wj * 64 + j * 16 + l15) * 32 + quad * 8];
        #pragma unroll
        for (int i = 0; i < 4; ++i)
            #pragma unroll
            for (int j = 0; j < 4; ++j)
                acc[i][j] = __builtin_amdgcn_mfma_f32_16x16x32_bf16(af[i], bf[j], acc[i][j], 0, 0, 0);
    }

    // C/D: col = l15, row = quad*4+reg. Within this jt tile: col index = t, d = jt.
    if (jt < 32) {
        const int d = jt;
        #pragma unroll
        for (int i = 0; i < 4; ++i)
            #pragma unroll
            for (int j = 0; j < 4; ++j) {
                const int t_ = wj * 64 + j * 16 + l15;
                #pragma unroll
                for (int reg = 0; reg < 4; ++reg) {
                    const int m_ = mt * 128 + wm * 64 + i * 16 + quad * 4 + reg;
                    ut[(((size_t)bi * 256 + m_) * 128 + t_) * 32 + d] = f2b(acc[i][j][reg]);
                }
            }
    } else {
        #pragma unroll
        for (int i = 0; i < 4; ++i)
            #pragma unroll
            for (int j = 0; j < 4; ++j) {
                const int t_ = wj * 64 + j * 16 + l15;
                #pragma unroll
                for (int reg = 0; reg < 4; ++reg) {
                    const int m_ = mt * 128 + wm * 64 + i * 16 + quad * 4 + reg;
                    sbuf[((size_t)bi * 256 + m_) * 128 + t_] = f2b(acc[i][j][reg]);
                }
            }
    }
}

// ---------- MFMA MLP: y = relu(bias + Wsum@ftT + r0*(W2@u0T) + r1*(W3@u1T)) ----------
// grid (256, 2). 4 waves; wave = o-tile. No LDS; frags straight from global.
__launch_bounds__(256)
__global__ void k_mlp(const unsigned short* __restrict__ ftT, const unsigned short* __restrict__ ut,
                      const unsigned short* __restrict__ sbuf, const unsigned short* __restrict__ Wb,
                      const float* __restrict__ bias, float* __restrict__ y) {
    const int m = blockIdx.x, b = blockIdx.y;
    const int tid = threadIdx.x;
    const int wave = tid >> 6, lane = tid & 63;
    const int l15 = lane & 15, quad = lane >> 4;

    const size_t wrow = (size_t)(wave * 16 + l15) * 32 + quad * 8;
    shortx8 aw = *(const shortx8*)(Wb + wrow);
    shortx8 a2 = *(const shortx8*)(Wb + 2048 + wrow);
    shortx8 a3 = *(const shortx8*)(Wb + 4096 + wrow);
    float bv[4];
    #pragma unroll
    for (int r = 0; r < 4; ++r) bv[r] = bias[wave * 16 + quad * 4 + r];

    const unsigned short* fp = ftT + ((size_t)(b * 256 + m) * 128) * 32;
    const unsigned short* u0 = ut + ((size_t)((2 * b + 0) * 256 + m) * 128) * 32;
    const unsigned short* u1 = ut + ((size_t)((2 * b + 1) * 256 + m) * 128) * 32;
    const unsigned short* s0 = sbuf + ((size_t)(2 * b + 0) * 256 + m) * 128;
    const unsigned short* s1 = sbuf + ((size_t)(2 * b + 1) * 256 + m) * 128;
    float* yp = y + ((size_t)(b * 256 + m) * 64) * 128;

    #pragma unroll
    for (int tt = 0; tt < 8; ++tt) {
        const int t = tt * 16 + l15;
        shortx8 bf = *(const shortx8*)(fp + (size_t)t * 32 + quad * 8);
        shortx8 b0 = *(const shortx8*)(u0 + (size_t)t * 32 + quad * 8);
        shortx8 b1 = *(const shortx8*)(u1 + (size_t)t * 32 + quad * 8);
        floatx4 z = {0.f, 0.f, 0.f, 0.f};
        floatx4 cw = __builtin_amdgcn_mfma_f32_16x16x32_bf16(aw, bf, z, 0, 0, 0);
        floatx4 c2 = __builtin_amdgcn_mfma_f32_16x16x32_bf16(a2, b0, z, 0, 0, 0);
        floatx4 c3 = __builtin_amdgcn_mfma_f32_16x16x32_bf16(a3, b1, z, 0, 0, 0);
        float r0 = 1.f / (b2f(s0[t]) + 1.f);
        float r1 = 1.f / (b2f(s1[t]) + 1.f);
        #pragma unroll
        for (int r = 0; r < 4; ++r) {
            const int o = wave * 16 + quad * 4 + r;
            float v = cw[r] + r0 * c2[r] + r1 * c3[r] + bv[r];
            yp[(size_t)o * 128 + t] = v > 0.f ? v : 0.f;
        }
    }
}

extern "C" void kernel_launch(void* const* d_in, const int* in_sizes, int n_in,
                              void* d_out, int out_size, void* d_ws, size_t ws_size,
                              hipStream_t stream) {
    const float* fc   = (const float*)d_in[0]; // [2,512,32,128]
    const float* ft   = (const float*)d_in[1]; // [2,256,32,128]
    const float* adj  = (const float*)d_in[2]; // [2,2,256,512]
    const float* mask = (const float*)d_in[3]; // [2,128,512]
    const float* W    = (const float*)d_in[4]; // [64,96]
    const float* bias = (const float*)d_in[5]; // [64]
    float* y = (float*)d_out;                  // [2,256,64,128]

    unsigned short* gt   = (unsigned short*)d_ws;            // [2][4224][512]
    unsigned short* adjb = gt   + (size_t)2 * 4224 * 512;    // [4][256][512]
    unsigned short* ut   = adjb + (size_t)4 * 256 * 512;     // [4][256][128][32]
    unsigned short* sbuf = ut   + (size_t)4 * 256 * 128 * 32;// [4][256][128]
    unsigned short* ftT  = sbuf + (size_t)4 * 256 * 128;     // [2][256][128][32]
    unsigned short* Wb   = ftT  + (size_t)2 * 256 * 128 * 32;// [3][64][32]
    // total ~22.6 MB

    k_adj <<<513, 256, 0, stream>>>(adj, W, adjb, Wb);
    k_g   <<<dim3(132, 16, 2), 256, 0, stream>>>(fc, mask, gt);
    k_ft  <<<dim3(256, 2), 256, 0, stream>>>(ft, ftT);
    k_gemm<<<dim3(33, 2, 4), 256, 0, stream>>>(adjb, gt, ut, sbuf);
    k_mlp <<<dim3(256, 2), 256, 0, stream>>>(ftT, ut, sbuf, Wb, bias, y);
}

// Round 6
// 113.199 us; speedup vs baseline: 1.3378x; 1.3378x over previous
//
#include <hip/hip_runtime.h>
#include <cstdint>
#include <cstddef>

// Shapes: b=2, n=512, m=256, d=32, t=128, ORDER=2, C_OUT=64. All I/O fp32.
// Pipeline:
//   k_adj : adj fp32 -> bf16 [4][256][512]; block 512 also builds
//           Wb[3][64][32] = bf16{W1+W2+W3, W2, W3} from W[64][96]
//   k_g   : gt[b][j][n] = bf16(fc[b][n][j] * (1-mask[b][t][n])), j=d*128+t<4096
//           gt[b][4096+t][n] = bf16(1-mask[b][t][n])   (s-channels)
//   k_ft  : ftT[b][m][t][d] = bf16(ft[b][m][d][t])     (MFMA B-operand layout)
//   k_gemm: MFMA 128x128 tile. jt<32: tile owns t0=jt*4..+3 x all 32 d
//           (row map jloc=tloc*32+d <-> gt row d*128+t0+tloc) so each output
//           64B line of ut[m][t][0..31] is written by ONE block (no RMW blowup).
//           jt==32: s[bi][m][t].
//   k_mlp : y = relu(bias + Wsum@ftT + r0*(W2@u0T) + r1*(W3@u1T)), r=1/(s+1)
//           pure-MFMA, no LDS, K=32 per GEMM.

using shortx8 = __attribute__((ext_vector_type(8))) short;
using floatx4 = __attribute__((ext_vector_type(4))) float;

__device__ __forceinline__ float b2f(unsigned short u) {
    union { unsigned int i; float f; } v; v.i = ((unsigned int)u) << 16; return v.f;
}
__device__ __forceinline__ unsigned short f2b(float f) {
    union { float f; unsigned int i; } v; v.f = f;
    unsigned int x = v.i;
    return (unsigned short)((x + 0x7FFFu + ((x >> 16) & 1u)) >> 16); // RNE
}
__device__ __forceinline__ void gl_lds16(const unsigned short* g, unsigned short* l) {
    __builtin_amdgcn_global_load_lds(
        (const __attribute__((address_space(1))) unsigned int*)g,
        (__attribute__((address_space(3))) unsigned int*)l, 16, 0, 0);
}

// ---------- adj fp32 -> bf16, plus W-prep in block 512 ----------
__global__ void k_adj(const float* __restrict__ adj, const float* __restrict__ W,
                      unsigned short* __restrict__ adjb, unsigned short* __restrict__ Wb) {
    if (blockIdx.x == 512) {
        for (int e = threadIdx.x; e < 2048; e += 256) {
            int o = e >> 5, d = e & 31;
            float w1 = W[o * 96 + d], w2 = W[o * 96 + 32 + d], w3 = W[o * 96 + 64 + d];
            Wb[e]        = f2b(w1 + w2 + w3);
            Wb[2048 + e] = f2b(w2);
            Wb[4096 + e] = f2b(w3);
        }
        return;
    }
    int i4 = (blockIdx.x * 256 + threadIdx.x) * 4;
    float4 v = *(const float4*)(adj + i4);
    ushort4 o;
    o.x = f2b(v.x); o.y = f2b(v.y); o.z = f2b(v.z); o.w = f2b(v.w);
    *(ushort4*)(adjb + i4) = o;
}

// ---------- build gt[b][j][n] (transposed, bf16, with s-channels) ----------
__global__ void k_g(const float* __restrict__ fc, const float* __restrict__ mask,
                    unsigned short* __restrict__ gt) {
    const int jb = blockIdx.x, nb = blockIdx.y, b = blockIdx.z;
    const int tid = threadIdx.x;
    const int n0 = nb * 32;
    const int r = tid >> 3, c4 = (tid & 7) * 4;
    if (jb >= 128) {
        const int t0 = (jb - 128) * 32;
        float4 mv = *(const float4*)(mask + ((size_t)b * 128 + t0 + r) * 512 + n0 + c4);
        ushort4 o;
        o.x = f2b(1.f - mv.x); o.y = f2b(1.f - mv.y);
        o.z = f2b(1.f - mv.z); o.w = f2b(1.f - mv.w);
        *(ushort4*)(gt + ((size_t)b * 4224 + 4096 + t0 + r) * 512 + n0 + c4) = o;
        return;
    }
    const int j0 = jb * 32;
    const int t0 = j0 & 127;
    __shared__ float wls[32][33];
    __shared__ unsigned short tls[32][34];
    {
        float4 mv = *(const float4*)(mask + ((size_t)b * 128 + t0 + r) * 512 + n0 + c4);
        wls[r][c4 + 0] = 1.f - mv.x; wls[r][c4 + 1] = 1.f - mv.y;
        wls[r][c4 + 2] = 1.f - mv.z; wls[r][c4 + 3] = 1.f - mv.w;
    }
    float4 fv = *(const float4*)(fc + ((size_t)b * 512 + n0 + r) * 4096 + j0 + c4);
    __syncthreads();
    tls[c4 + 0][r] = f2b(fv.x * wls[c4 + 0][r]);
    tls[c4 + 1][r] = f2b(fv.y * wls[c4 + 1][r]);
    tls[c4 + 2][r] = f2b(fv.z * wls[c4 + 2][r]);
    tls[c4 + 3][r] = f2b(fv.w * wls[c4 + 3][r]);
    __syncthreads();
    ushort4 o;
    o.x = tls[r][c4 + 0]; o.y = tls[r][c4 + 1];
    o.z = tls[r][c4 + 2]; o.w = tls[r][c4 + 3];
    *(ushort4*)(gt + ((size_t)b * 4224 + j0 + r) * 512 + n0 + c4) = o;
}

// ---------- ftT[b][m][t][d] = bf16(ft[b][m][d][t]) ----------
__global__ void k_ft(const float* __restrict__ ft, unsigned short* __restrict__ ftT) {
    const int m = blockIdx.x, b = blockIdx.y;
    const int tid = threadIdx.x;
    __shared__ unsigned short l[32][136];
    const float* src = ft + ((size_t)(b * 256 + m) * 32) * 128;
    {
        const int d = tid >> 3, t0 = (tid & 7) * 16;
        float4 v0 = *(const float4*)(src + (size_t)d * 128 + t0);
        float4 v1 = *(const float4*)(src + (size_t)d * 128 + t0 + 4);
        float4 v2 = *(const float4*)(src + (size_t)d * 128 + t0 + 8);
        float4 v3 = *(const float4*)(src + (size_t)d * 128 + t0 + 12);
        unsigned short* p = &l[d][t0];
        p[0]  = f2b(v0.x); p[1]  = f2b(v0.y); p[2]  = f2b(v0.z); p[3]  = f2b(v0.w);
        p[4]  = f2b(v1.x); p[5]  = f2b(v1.y); p[6]  = f2b(v1.z); p[7]  = f2b(v1.w);
        p[8]  = f2b(v2.x); p[9]  = f2b(v2.y); p[10] = f2b(v2.z); p[11] = f2b(v2.w);
        p[12] = f2b(v3.x); p[13] = f2b(v3.y); p[14] = f2b(v3.z); p[15] = f2b(v3.w);
    }
    __syncthreads();
    {
        const int t = tid & 127, dh = (tid >> 7) * 16;
        unsigned short tmp[16];
        #pragma unroll
        for (int k = 0; k < 16; ++k) tmp[k] = l[dh + k][t];
        unsigned short* dst = ftT + ((size_t)(b * 256 + m) * 128 + t) * 32 + dh;
        *(shortx8*)(dst)     = *(const shortx8*)(tmp);
        *(shortx8*)(dst + 8) = *(const shortx8*)(tmp + 8);
    }
}

// ---------- MFMA GEMM: ut[bi][m][t][d] / s[bi][m][t] ----------
// grid (33, 2, 4). jt<32: t0=jt*4, tile rows jloc = tloc*32+d. jt==32: s rows.
__launch_bounds__(256, 1)
__global__ void k_gemm(const unsigned short* __restrict__ adjb,
                       const unsigned short* __restrict__ gt,
                       unsigned short* __restrict__ ut,
                       unsigned short* __restrict__ sbuf) {
    const int jt = blockIdx.x, mt = blockIdx.y, bi = blockIdx.z;
    const int b = bi >> 1;
    const int tid = threadIdx.x;
    const int wave = tid >> 6, lane = tid & 63;
    const int l15 = lane & 15, quad = lane >> 4;
    const int wm = wave >> 1, wj = wave & 1;

    __shared__ __align__(16) unsigned short Al[128 * 32];
    __shared__ __align__(16) unsigned short Bl[128 * 32];

    const int srow = lane >> 2;          // row within 16-row chunk
    const int skq  = (lane & 3) * 8;     // k-slot (8 shorts)
    const unsigned short* Ag = adjb + ((size_t)bi * 256 + mt * 128) * 512;
    const unsigned short* Bgb = gt + (size_t)b * 4224 * 512;

    // B row map: tile-local row r -> gt row j
    //   jt<32 : j = (r&31)*128 + jt*4 + (r>>5)
    //   jt==32: j = 4096 + r
    floatx4 acc[4][4];
    #pragma unroll
    for (int i = 0; i < 4; ++i)
        #pragma unroll
        for (int j = 0; j < 4; ++j) acc[i][j] = (floatx4){0.f, 0.f, 0.f, 0.f};

    for (int k0 = 0; k0 < 512; k0 += 32) {
        __syncthreads();
        #pragma unroll
        for (int rr = 0; rr < 2; ++rr) {
            const int ch = wave * 2 + rr;
            const int row = ch * 16 + srow;
            gl_lds16(Ag + (size_t)row * 512 + k0 + skq, &Al[ch * 512]);
            const int jrow = (jt < 32) ? ((row & 31) * 128 + jt * 4 + (row >> 5))
                                       : (4096 + row);
            gl_lds16(Bgb + (size_t)jrow * 512 + k0 + skq, &Bl[ch * 512]);
        }
        __syncthreads();

        shortx8 af[4], bf[4];
        #pragma unroll
        for (int i = 0; i < 4; ++i)
            af[i] = *(const shortx8*)&Al[(wm * 64 + i * 16 + l15) * 32 + quad * 8];
        #pragma unroll
        for (int j = 0; j < 4; ++j)
            bf[j] = *(const shortx8*)&Bl[(wj * 64 + j * 16 + l15) * 32 + quad * 8];
        #pragma unroll
        for (int i = 0; i < 4; ++i)
            #pragma unroll
            for (int j = 0; j < 4; ++j)
                acc[i][j] = __builtin_amdgcn_mfma_f32_16x16x32_bf16(af[i], bf[j], acc[i][j], 0, 0, 0);
    }

    // C/D: col(jloc) = wj*64 + jj*16 + l15, row(m) = wm*64 + i*16 + quad*4 + reg
    if (jt < 32) {
        #pragma unroll
        for (int i = 0; i < 4; ++i)
            #pragma unroll
            for (int jj = 0; jj < 4; ++jj) {
                const int d_   = (jj & 1) * 16 + l15;      // jloc & 31
                const int tloc = wj * 2 + (jj >> 1);       // jloc >> 5
                const int t_   = jt * 4 + tloc;
                #pragma unroll
                for (int reg = 0; reg < 4; ++reg) {
                    const int m_ = mt * 128 + wm * 64 + i * 16 + quad * 4 + reg;
                    ut[(((size_t)bi * 256 + m_) * 128 + t_) * 32 + d_] = f2b(acc[i][jj][reg]);
                }
            }
    } else {
        #pragma unroll
        for (int i = 0; i < 4; ++i)
            #pragma unroll
            for (int jj = 0; jj < 4; ++jj) {
                const int t_ = wj * 64 + jj * 16 + l15;
                #pragma unroll
                for (int reg = 0; reg < 4; ++reg) {
                    const int m_ = mt * 128 + wm * 64 + i * 16 + quad * 4 + reg;
                    sbuf[((size_t)bi * 256 + m_) * 128 + t_] = f2b(acc[i][jj][reg]);
                }
            }
    }
}

// ---------- MFMA MLP: y = relu(bias + Wsum@ftT + r0*(W2@u0T) + r1*(W3@u1T)) ----------
__launch_bounds__(256)
__global__ void k_mlp(const unsigned short* __restrict__ ftT, const unsigned short* __restrict__ ut,
                      const unsigned short* __restrict__ sbuf, const unsigned short* __restrict__ Wb,
                      const float* __restrict__ bias, float* __restrict__ y) {
    const int m = blockIdx.x, b = blockIdx.y;
    const int tid = threadIdx.x;
    const int wave = tid >> 6, lane = tid & 63;
    const int l15 = lane & 15, quad = lane >> 4;

    const size_t wrow = (size_t)(wave * 16 + l15) * 32 + quad * 8;
    shortx8 aw = *(const shortx8*)(Wb + wrow);
    shortx8 a2 = *(const shortx8*)(Wb + 2048 + wrow);
    shortx8 a3 = *(const shortx8*)(Wb + 4096 + wrow);
    float bv[4];
    #pragma unroll
    for (int r = 0; r < 4; ++r) bv[r] = bias[wave * 16 + quad * 4 + r];

    const unsigned short* fp = ftT + ((size_t)(b * 256 + m) * 128) * 32;
    const unsigned short* u0 = ut + ((size_t)((2 * b + 0) * 256 + m) * 128) * 32;
    const unsigned short* u1 = ut + ((size_t)((2 * b + 1) * 256 + m) * 128) * 32;
    const unsigned short* s0 = sbuf + ((size_t)(2 * b + 0) * 256 + m) * 128;
    const unsigned short* s1 = sbuf + ((size_t)(2 * b + 1) * 256 + m) * 128;
    float* yp = y + ((size_t)(b * 256 + m) * 64) * 128;

    #pragma unroll
    for (int tt = 0; tt < 8; ++tt) {
        const int t = tt * 16 + l15;
        shortx8 bf = *(const shortx8*)(fp + (size_t)t * 32 + quad * 8);
        shortx8 b0 = *(const shortx8*)(u0 + (size_t)t * 32 + quad * 8);
        shortx8 b1 = *(const shortx8*)(u1 + (size_t)t * 32 + quad * 8);
        floatx4 z = {0.f, 0.f, 0.f, 0.f};
        floatx4 cw = __builtin_amdgcn_mfma_f32_16x16x32_bf16(aw, bf, z, 0, 0, 0);
        floatx4 c2 = __builtin_amdgcn_mfma_f32_16x16x32_bf16(a2, b0, z, 0, 0, 0);
        floatx4 c3 = __builtin_amdgcn_mfma_f32_16x16x32_bf16(a3, b1, z, 0, 0, 0);
        float r0 = 1.f / (b2f(s0[t]) + 1.f);
        float r1 = 1.f / (b2f(s1[t]) + 1.f);
        #pragma unroll
        for (int r = 0; r < 4; ++r) {
            const int o = wave * 16 + quad * 4 + r;
            float v = cw[r] + r0 * c2[r] + r1 * c3[r] + bv[r];
            yp[(size_t)o * 128 + t] = v > 0.f ? v : 0.f;
        }
    }
}

extern "C" void kernel_launch(void* const* d_in, const int* in_sizes, int n_in,
                              void* d_out, int out_size, void* d_ws, size_t ws_size,
                              hipStream_t stream) {
    const float* fc   = (const float*)d_in[0]; // [2,512,32,128]
    const float* ft   = (const float*)d_in[1]; // [2,256,32,128]
    const float* adj  = (const float*)d_in[2]; // [2,2,256,512]
    const float* mask = (const float*)d_in[3]; // [2,128,512]
    const float* W    = (const float*)d_in[4]; // [64,96]
    const float* bias = (const float*)d_in[5]; // [64]
    float* y = (float*)d_out;                  // [2,256,64,128]

    unsigned short* gt   = (unsigned short*)d_ws;            // [2][4224][512]
    unsigned short* adjb = gt   + (size_t)2 * 4224 * 512;    // [4][256][512]
    unsigned short* ut   = adjb + (size_t)4 * 256 * 512;     // [4][256][128][32]
    unsigned short* sbuf = ut   + (size_t)4 * 256 * 128 * 32;// [4][256][128]
    unsigned short* ftT  = sbuf + (size_t)4 * 256 * 128;     // [2][256][128][32]
    unsigned short* Wb   = ftT  + (size_t)2 * 256 * 128 * 32;// [3][64][32]
    // total ~22.6 MB

    k_adj <<<513, 256, 0, stream>>>(adj, W, adjb, Wb);
    k_g   <<<dim3(132, 16, 2), 256, 0, stream>>>(fc, mask, gt);
    k_ft  <<<dim3(256, 2), 256, 0, stream>>>(ft, ftT);
    k_gemm<<<dim3(33, 2, 4), 256, 0, stream>>>(adjb, gt, ut, sbuf);
    k_mlp <<<dim3(256, 2), 256, 0, stream>>>(ftT, ut, sbuf, Wb, bias, y);
}

// Round 7
// 110.859 us; speedup vs baseline: 1.3660x; 1.0211x over previous
//
#include <hip/hip_runtime.h>
#include <cstdint>
#include <cstddef>

// Shapes: b=2, n=512, m=256, d=32, t=128, ORDER=2, C_OUT=64. All I/O fp32.
// Pipeline:
//   k_prep: fused  (a) gt[b][j][n] = bf16(fc[b][n][j]*(1-mask[b][t][n])) + s-channels
//                  (b) adj fp32->bf16, (c) Wb prep, (d) ftT[b][m][t][d] = bf16(ft)
//   k_gemm: MFMA 128x128 tile, BK=64, double-buffered LDS (1 barrier/iter).
//           jt<32: tile owns t0=jt*4..+3 x all 32 d (row map jloc=tloc*32+d) ->
//           ut[bi][m][t][d]; jt==32: s[bi][m][t]. One block owns each 64B out line.
//   k_mlp : y = relu(bias + Wsum@ftT + r0*(W2@u0T) + r1*(W3@u1T)), r=1/(s+1)
//           pure-MFMA, no LDS, K=32 per GEMM.

using shortx8 = __attribute__((ext_vector_type(8))) short;
using floatx4 = __attribute__((ext_vector_type(4))) float;

__device__ __forceinline__ float b2f(unsigned short u) {
    union { unsigned int i; float f; } v; v.i = ((unsigned int)u) << 16; return v.f;
}
__device__ __forceinline__ unsigned short f2b(float f) {
    union { float f; unsigned int i; } v; v.f = f;
    unsigned int x = v.i;
    return (unsigned short)((x + 0x7FFFu + ((x >> 16) & 1u)) >> 16); // RNE
}
__device__ __forceinline__ void gl_lds16(const unsigned short* g, unsigned short* l) {
    __builtin_amdgcn_global_load_lds(
        (const __attribute__((address_space(1))) unsigned int*)g,
        (__attribute__((address_space(3))) unsigned int*)l, 16, 0, 0);
}

// ---------- fused prep ----------
// blocks [0,4224)      : gt build   (jb = r%132, nb = (r/132)%16, b = r/2112)
// blocks [4224,4736)   : adj->bf16
// block  4736          : Wb prep
// blocks [4737,5249)   : ftT build
__global__ void k_prep(const float* __restrict__ fc, const float* __restrict__ mask,
                       const float* __restrict__ adj, const float* __restrict__ W,
                       const float* __restrict__ ft,
                       unsigned short* __restrict__ gt, unsigned short* __restrict__ adjb,
                       unsigned short* __restrict__ Wb, unsigned short* __restrict__ ftT) {
    const int tid = threadIdx.x;
    __shared__ float wls[32][33];
    __shared__ unsigned short tls[32][34];
    __shared__ unsigned short ftl[32][136];

    if (blockIdx.x < 4224) {  // ---- gt ----
        const int r_ = blockIdx.x;
        const int jb = r_ % 132;
        const int rem = r_ / 132;
        const int nb = rem & 15, b = rem >> 4;
        const int n0 = nb * 32;
        const int r = tid >> 3, c4 = (tid & 7) * 4;
        if (jb >= 128) {
            const int t0 = (jb - 128) * 32;
            float4 mv = *(const float4*)(mask + ((size_t)b * 128 + t0 + r) * 512 + n0 + c4);
            ushort4 o;
            o.x = f2b(1.f - mv.x); o.y = f2b(1.f - mv.y);
            o.z = f2b(1.f - mv.z); o.w = f2b(1.f - mv.w);
            *(ushort4*)(gt + ((size_t)b * 4224 + 4096 + t0 + r) * 512 + n0 + c4) = o;
            return;
        }
        const int j0 = jb * 32;
        const int t0 = j0 & 127;
        {
            float4 mv = *(const float4*)(mask + ((size_t)b * 128 + t0 + r) * 512 + n0 + c4);
            wls[r][c4 + 0] = 1.f - mv.x; wls[r][c4 + 1] = 1.f - mv.y;
            wls[r][c4 + 2] = 1.f - mv.z; wls[r][c4 + 3] = 1.f - mv.w;
        }
        float4 fv = *(const float4*)(fc + ((size_t)b * 512 + n0 + r) * 4096 + j0 + c4);
        __syncthreads();
        tls[c4 + 0][r] = f2b(fv.x * wls[c4 + 0][r]);
        tls[c4 + 1][r] = f2b(fv.y * wls[c4 + 1][r]);
        tls[c4 + 2][r] = f2b(fv.z * wls[c4 + 2][r]);
        tls[c4 + 3][r] = f2b(fv.w * wls[c4 + 3][r]);
        __syncthreads();
        ushort4 o;
        o.x = tls[r][c4 + 0]; o.y = tls[r][c4 + 1];
        o.z = tls[r][c4 + 2]; o.w = tls[r][c4 + 3];
        *(ushort4*)(gt + ((size_t)b * 4224 + j0 + r) * 512 + n0 + c4) = o;
    } else if (blockIdx.x < 4736) {  // ---- adj ----
        int i4 = ((blockIdx.x - 4224) * 256 + tid) * 4;
        float4 v = *(const float4*)(adj + i4);
        ushort4 o;
        o.x = f2b(v.x); o.y = f2b(v.y); o.z = f2b(v.z); o.w = f2b(v.w);
        *(ushort4*)(adjb + i4) = o;
    } else if (blockIdx.x == 4736) {  // ---- Wb ----
        for (int e = tid; e < 2048; e += 256) {
            int o = e >> 5, d = e & 31;
            float w1 = W[o * 96 + d], w2 = W[o * 96 + 32 + d], w3 = W[o * 96 + 64 + d];
            Wb[e]        = f2b(w1 + w2 + w3);
            Wb[2048 + e] = f2b(w2);
            Wb[4096 + e] = f2b(w3);
        }
    } else {  // ---- ftT ----
        const int fb = blockIdx.x - 4737;
        const int m = fb & 255, b = fb >> 8;
        const float* src = ft + ((size_t)(b * 256 + m) * 32) * 128;
        {
            const int d = tid >> 3, t0 = (tid & 7) * 16;
            float4 v0 = *(const float4*)(src + (size_t)d * 128 + t0);
            float4 v1 = *(const float4*)(src + (size_t)d * 128 + t0 + 4);
            float4 v2 = *(const float4*)(src + (size_t)d * 128 + t0 + 8);
            float4 v3 = *(const float4*)(src + (size_t)d * 128 + t0 + 12);
            unsigned short* p = &ftl[d][t0];
            p[0]  = f2b(v0.x); p[1]  = f2b(v0.y); p[2]  = f2b(v0.z); p[3]  = f2b(v0.w);
            p[4]  = f2b(v1.x); p[5]  = f2b(v1.y); p[6]  = f2b(v1.z); p[7]  = f2b(v1.w);
            p[8]  = f2b(v2.x); p[9]  = f2b(v2.y); p[10] = f2b(v2.z); p[11] = f2b(v2.w);
            p[12] = f2b(v3.x); p[13] = f2b(v3.y); p[14] = f2b(v3.z); p[15] = f2b(v3.w);
        }
        __syncthreads();
        {
            const int t = tid & 127, dh = (tid >> 7) * 16;
            unsigned short tmp[16];
            #pragma unroll
            for (int k = 0; k < 16; ++k) tmp[k] = ftl[dh + k][t];
            unsigned short* dst = ftT + ((size_t)(b * 256 + m) * 128 + t) * 32 + dh;
            *(shortx8*)(dst)     = *(const shortx8*)(tmp);
            *(shortx8*)(dst + 8) = *(const shortx8*)(tmp + 8);
        }
    }
}

// ---------- MFMA GEMM, BK=64, double-buffered: ut[bi][m][t][d] / s[bi][m][t] ----------
// grid (33, 2, 4). jt<32: t0=jt*4, tile rows jloc = tloc*32+d. jt==32: s rows.
__launch_bounds__(256, 1)
__global__ void k_gemm(const unsigned short* __restrict__ adjb,
                       const unsigned short* __restrict__ gt,
                       unsigned short* __restrict__ ut,
                       unsigned short* __restrict__ sbuf) {
    const int jt = blockIdx.x, mt = blockIdx.y, bi = blockIdx.z;
    const int b = bi >> 1;
    const int tid = threadIdx.x;
    const int wave = tid >> 6, lane = tid & 63;
    const int l15 = lane & 15, quad = lane >> 4;
    const int wm = wave >> 1, wj = wave & 1;

    __shared__ __align__(16) unsigned short Al[2][128 * 64];  // 2 x 16 KB
    __shared__ __align__(16) unsigned short Bl[2][128 * 64];  // 2 x 16 KB

    // staging: chunk = 64 lanes * 16B = 512 shorts = 8 rows of 64; 16 chunks/buf.
    const int srow = lane >> 3;          // 0..7 row within chunk
    const int skq  = (lane & 7) * 8;     // 0..56 k-slot (8 shorts)
    const unsigned short* Ag = adjb + ((size_t)bi * 256 + mt * 128) * 512;
    const unsigned short* Bgb = gt + (size_t)b * 4224 * 512;

    // B row map: tile-local row r -> gt row j
    //   jt<32 : j = (r&31)*128 + jt*4 + (r>>5)     jt==32: j = 4096 + r
    #define STAGE(buf, k0)                                                        \
        _Pragma("unroll")                                                         \
        for (int rr = 0; rr < 4; ++rr) {                                          \
            const int ch = wave * 4 + rr;                                         \
            const int row = ch * 8 + srow;                                        \
            gl_lds16(Ag + (size_t)row * 512 + (k0) + skq, &Al[buf][ch * 512]);    \
            const int jrow = (jt < 32) ? ((row & 31) * 128 + jt * 4 + (row >> 5)) \
                                       : (4096 + row);                            \
            gl_lds16(Bgb + (size_t)jrow * 512 + (k0) + skq, &Bl[buf][ch * 512]);  \
        }

    floatx4 acc[4][4];
    #pragma unroll
    for (int i = 0; i < 4; ++i)
        #pragma unroll
        for (int j = 0; j < 4; ++j) acc[i][j] = (floatx4){0.f, 0.f, 0.f, 0.f};

    STAGE(0, 0)
    int cur = 0;
    for (int it = 0; it < 8; ++it) {
        __syncthreads();                 // compiler drains vmcnt -> buf[cur] ready
        if (it < 7) { STAGE(cur ^ 1, (it + 1) * 64) }   // prefetch flies during MFMA
        #pragma unroll
        for (int ks = 0; ks < 2; ++ks) {
            shortx8 af[4], bf[4];
            #pragma unroll
            for (int i = 0; i < 4; ++i)
                af[i] = *(const shortx8*)&Al[cur][(wm * 64 + i * 16 + l15) * 64 + ks * 32 + quad * 8];
            #pragma unroll
            for (int j = 0; j < 4; ++j)
                bf[j] = *(const shortx8*)&Bl[cur][(wj * 64 + j * 16 + l15) * 64 + ks * 32 + quad * 8];
            #pragma unroll
            for (int i = 0; i < 4; ++i)
                #pragma unroll
                for (int j = 0; j < 4; ++j)
                    acc[i][j] = __builtin_amdgcn_mfma_f32_16x16x32_bf16(af[i], bf[j], acc[i][j], 0, 0, 0);
        }
        cur ^= 1;
    }
    #undef STAGE

    // C/D: col(jloc) = wj*64 + jj*16 + l15, row(m) = wm*64 + i*16 + quad*4 + reg
    if (jt < 32) {
        #pragma unroll
        for (int i = 0; i < 4; ++i)
            #pragma unroll
            for (int jj = 0; jj < 4; ++jj) {
                const int d_   = (jj & 1) * 16 + l15;      // jloc & 31
                const int tloc = wj * 2 + (jj >> 1);       // jloc >> 5
                const int t_   = jt * 4 + tloc;
                #pragma unroll
                for (int reg = 0; reg < 4; ++reg) {
                    const int m_ = mt * 128 + wm * 64 + i * 16 + quad * 4 + reg;
                    ut[(((size_t)bi * 256 + m_) * 128 + t_) * 32 + d_] = f2b(acc[i][jj][reg]);
                }
            }
    } else {
        #pragma unroll
        for (int i = 0; i < 4; ++i)
            #pragma unroll
            for (int jj = 0; jj < 4; ++jj) {
                const int t_ = wj * 64 + jj * 16 + l15;
                #pragma unroll
                for (int reg = 0; reg < 4; ++reg) {
                    const int m_ = mt * 128 + wm * 64 + i * 16 + quad * 4 + reg;
                    sbuf[((size_t)bi * 256 + m_) * 128 + t_] = f2b(acc[i][jj][reg]);
                }
            }
    }
}

// ---------- MFMA MLP: y = relu(bias + Wsum@ftT + r0*(W2@u0T) + r1*(W3@u1T)) ----------
__launch_bounds__(256)
__global__ void k_mlp(const unsigned short* __restrict__ ftT, const unsigned short* __restrict__ ut,
                      const unsigned short* __restrict__ sbuf, const unsigned short* __restrict__ Wb,
                      const float* __restrict__ bias, float* __restrict__ y) {
    const int m = blockIdx.x, b = blockIdx.y;
    const int tid = threadIdx.x;
    const int wave = tid >> 6, lane = tid & 63;
    const int l15 = lane & 15, quad = lane >> 4;

    const size_t wrow = (size_t)(wave * 16 + l15) * 32 + quad * 8;
    shortx8 aw = *(const shortx8*)(Wb + wrow);
    shortx8 a2 = *(const shortx8*)(Wb + 2048 + wrow);
    shortx8 a3 = *(const shortx8*)(Wb + 4096 + wrow);
    float bv[4];
    #pragma unroll
    for (int r = 0; r < 4; ++r) bv[r] = bias[wave * 16 + quad * 4 + r];

    const unsigned short* fp = ftT + ((size_t)(b * 256 + m) * 128) * 32;
    const unsigned short* u0 = ut + ((size_t)((2 * b + 0) * 256 + m) * 128) * 32;
    const unsigned short* u1 = ut + ((size_t)((2 * b + 1) * 256 + m) * 128) * 32;
    const unsigned short* s0 = sbuf + ((size_t)(2 * b + 0) * 256 + m) * 128;
    const unsigned short* s1 = sbuf + ((size_t)(2 * b + 1) * 256 + m) * 128;
    float* yp = y + ((size_t)(b * 256 + m) * 64) * 128;

    #pragma unroll
    for (int tt = 0; tt < 8; ++tt) {
        const int t = tt * 16 + l15;
        shortx8 bf = *(const shortx8*)(fp + (size_t)t * 32 + quad * 8);
        shortx8 b0 = *(const shortx8*)(u0 + (size_t)t * 32 + quad * 8);
        shortx8 b1 = *(const shortx8*)(u1 + (size_t)t * 32 + quad * 8);
        floatx4 z = {0.f, 0.f, 0.f, 0.f};
        floatx4 cw = __builtin_amdgcn_mfma_f32_16x16x32_bf16(aw, bf, z, 0, 0, 0);
        floatx4 c2 = __builtin_amdgcn_mfma_f32_16x16x32_bf16(a2, b0, z, 0, 0, 0);
        floatx4 c3 = __builtin_amdgcn_mfma_f32_16x16x32_bf16(a3, b1, z, 0, 0, 0);
        float r0 = 1.f / (b2f(s0[t]) + 1.f);
        float r1 = 1.f / (b2f(s1[t]) + 1.f);
        #pragma unroll
        for (int r = 0; r < 4; ++r) {
            const int o = wave * 16 + quad * 4 + r;
            float v = cw[r] + r0 * c2[r] + r1 * c3[r] + bv[r];
            yp[(size_t)o * 128 + t] = v > 0.f ? v : 0.f;
        }
    }
}

extern "C" void kernel_launch(void* const* d_in, const int* in_sizes, int n_in,
                              void* d_out, int out_size, void* d_ws, size_t ws_size,
                              hipStream_t stream) {
    const float* fc   = (const float*)d_in[0]; // [2,512,32,128]
    const float* ft   = (const float*)d_in[1]; // [2,256,32,128]
    const float* adj  = (const float*)d_in[2]; // [2,2,256,512]
    const float* mask = (const float*)d_in[3]; // [2,128,512]
    const float* W    = (const float*)d_in[4]; // [64,96]
    const float* bias = (const float*)d_in[5]; // [64]
    float* y = (float*)d_out;                  // [2,256,64,128]

    unsigned short* gt   = (unsigned short*)d_ws;            // [2][4224][512]
    unsigned short* adjb = gt   + (size_t)2 * 4224 * 512;    // [4][256][512]
    unsigned short* ut   = adjb + (size_t)4 * 256 * 512;     // [4][256][128][32]
    unsigned short* sbuf = ut   + (size_t)4 * 256 * 128 * 32;// [4][256][128]
    unsigned short* ftT  = sbuf + (size_t)4 * 256 * 128;     // [2][256][128][32]
    unsigned short* Wb   = ftT  + (size_t)2 * 256 * 128 * 32;// [3][64][32]
    // total ~22.6 MB

    k_prep<<<5249, 256, 0, stream>>>(fc, mask, adj, W, ft, gt, adjb, Wb, ftT);
    k_gemm<<<dim3(33, 2, 4), 256, 0, stream>>>(adjb, gt, ut, sbuf);
    k_mlp <<<dim3(256, 2), 256, 0, stream>>>(ftT, ut, sbuf, Wb, bias, y);
}

// Round 8
// 109.114 us; speedup vs baseline: 1.3879x; 1.0160x over previous
//
#include <hip/hip_runtime.h>
#include <cstdint>
#include <cstddef>

// Shapes: b=2, n=512, m=256, d=32, t=128, ORDER=2, C_OUT=64. All I/O fp32.
// Pipeline:
//   k_prep: (a) gt[b][j][n] = bf16(fc[b][n][j]*(1-mask[b][t][n])), j=d*128+t<4096;
//               gt[b][4096+t][n] = bf16(1-mask[b][t][n])   (s-channels)
//           (b) adj fp32->bf16
//   k_gemm: MFMA 64x128 tile, BK=64, double-buffered LDS, 2 blocks/CU.
//           jt<32: tile owns t0=jt*4..+3 x all 32 d -> ut[bi][m][t][d]
//           jt==32: s[bi][m][t]. One block owns each 64B output line.
//   k_mlp : y = relu(bias + Wsum@ftT + r0*(W2@u0T) + r1*(W3@u1T)), r=1/(s+1).
//           ft transposed in-LDS; W fragments built in-register from fp32.

using shortx8 = __attribute__((ext_vector_type(8))) short;
using floatx4 = __attribute__((ext_vector_type(4))) float;

__device__ __forceinline__ float b2f(unsigned short u) {
    union { unsigned int i; float f; } v; v.i = ((unsigned int)u) << 16; return v.f;
}
__device__ __forceinline__ unsigned short f2b(float f) {
    union { float f; unsigned int i; } v; v.f = f;
    unsigned int x = v.i;
    return (unsigned short)((x + 0x7FFFu + ((x >> 16) & 1u)) >> 16); // RNE
}
__device__ __forceinline__ void gl_lds16(const unsigned short* g, unsigned short* l) {
    __builtin_amdgcn_global_load_lds(
        (const __attribute__((address_space(1))) unsigned int*)g,
        (__attribute__((address_space(3))) unsigned int*)l, 16, 0, 0);
}

// ---------- fused prep: gt build [0,4224) + adj->bf16 [4224,4736) ----------
__global__ void k_prep(const float* __restrict__ fc, const float* __restrict__ mask,
                       const float* __restrict__ adj,
                       unsigned short* __restrict__ gt, unsigned short* __restrict__ adjb) {
    const int tid = threadIdx.x;
    __shared__ float wls[32][33];
    __shared__ unsigned short tls[32][34];

    if (blockIdx.x < 4224) {  // ---- gt ----
        const int r_ = blockIdx.x;
        const int jb = r_ % 132;
        const int rem = r_ / 132;
        const int nb = rem & 15, b = rem >> 4;
        const int n0 = nb * 32;
        const int r = tid >> 3, c4 = (tid & 7) * 4;
        if (jb >= 128) {
            const int t0 = (jb - 128) * 32;
            float4 mv = *(const float4*)(mask + ((size_t)b * 128 + t0 + r) * 512 + n0 + c4);
            ushort4 o;
            o.x = f2b(1.f - mv.x); o.y = f2b(1.f - mv.y);
            o.z = f2b(1.f - mv.z); o.w = f2b(1.f - mv.w);
            *(ushort4*)(gt + ((size_t)b * 4224 + 4096 + t0 + r) * 512 + n0 + c4) = o;
            return;
        }
        const int j0 = jb * 32;
        const int t0 = j0 & 127;
        {
            float4 mv = *(const float4*)(mask + ((size_t)b * 128 + t0 + r) * 512 + n0 + c4);
            wls[r][c4 + 0] = 1.f - mv.x; wls[r][c4 + 1] = 1.f - mv.y;
            wls[r][c4 + 2] = 1.f - mv.z; wls[r][c4 + 3] = 1.f - mv.w;
        }
        float4 fv = *(const float4*)(fc + ((size_t)b * 512 + n0 + r) * 4096 + j0 + c4);
        __syncthreads();
        tls[c4 + 0][r] = f2b(fv.x * wls[c4 + 0][r]);
        tls[c4 + 1][r] = f2b(fv.y * wls[c4 + 1][r]);
        tls[c4 + 2][r] = f2b(fv.z * wls[c4 + 2][r]);
        tls[c4 + 3][r] = f2b(fv.w * wls[c4 + 3][r]);
        __syncthreads();
        ushort4 o;
        o.x = tls[r][c4 + 0]; o.y = tls[r][c4 + 1];
        o.z = tls[r][c4 + 2]; o.w = tls[r][c4 + 3];
        *(ushort4*)(gt + ((size_t)b * 4224 + j0 + r) * 512 + n0 + c4) = o;
    } else {  // ---- adj ----
        int i4 = ((blockIdx.x - 4224) * 256 + tid) * 4;
        float4 v = *(const float4*)(adj + i4);
        ushort4 o;
        o.x = f2b(v.x); o.y = f2b(v.y); o.z = f2b(v.z); o.w = f2b(v.w);
        *(ushort4*)(adjb + i4) = o;
    }
}

// ---------- MFMA GEMM, 64x128 tile, BK=64, double-buffered ----------
// grid (33, 4, 4): jt, mt (64-wide m), bi. 4 waves; wave (w&1)=m-half, (w>>1)=j-half.
__launch_bounds__(256, 2)
__global__ void k_gemm(const unsigned short* __restrict__ adjb,
                       const unsigned short* __restrict__ gt,
                       unsigned short* __restrict__ ut,
                       unsigned short* __restrict__ sbuf) {
    const int jt = blockIdx.x, mt = blockIdx.y, bi = blockIdx.z;
    const int b = bi >> 1;
    const int tid = threadIdx.x;
    const int wave = tid >> 6, lane = tid & 63;
    const int l15 = lane & 15, quad = lane >> 4;
    const int wm = wave & 1, wj = wave >> 1;

    __shared__ __align__(16) unsigned short Al[2][64 * 64];   // 2 x 8 KB
    __shared__ __align__(16) unsigned short Bl[2][128 * 64];  // 2 x 16 KB

    const int srow = lane >> 3;          // 0..7 row within 8-row chunk
    const int skq  = (lane & 7) * 8;     // 0..56 k-slot (8 shorts)
    const unsigned short* Ag = adjb + ((size_t)bi * 256 + mt * 64) * 512;
    const unsigned short* Bgb = gt + (size_t)b * 4224 * 512;

    // B row map: tile-local row r -> gt row j
    //   jt<32 : j = (r&31)*128 + jt*4 + (r>>5)     jt==32: j = 4096 + r
    #define STAGE(buf, k0)                                                        \
        _Pragma("unroll")                                                         \
        for (int rr = 0; rr < 2; ++rr) {                                          \
            const int ch = wave * 2 + rr;        /* A chunks 0..7 */              \
            const int row = ch * 8 + srow;                                        \
            gl_lds16(Ag + (size_t)row * 512 + (k0) + skq, &Al[buf][ch * 512]);    \
        }                                                                         \
        _Pragma("unroll")                                                         \
        for (int rr = 0; rr < 4; ++rr) {                                          \
            const int ch = wave * 4 + rr;        /* B chunks 0..15 */             \
            const int row = ch * 8 + srow;                                        \
            const int jrow = (jt < 32) ? ((row & 31) * 128 + jt * 4 + (row >> 5)) \
                                       : (4096 + row);                            \
            gl_lds16(Bgb + (size_t)jrow * 512 + (k0) + skq, &Bl[buf][ch * 512]);  \
        }

    floatx4 acc[2][4];
    #pragma unroll
    for (int i = 0; i < 2; ++i)
        #pragma unroll
        for (int j = 0; j < 4; ++j) acc[i][j] = (floatx4){0.f, 0.f, 0.f, 0.f};

    STAGE(0, 0)
    int cur = 0;
    for (int it = 0; it < 8; ++it) {
        __syncthreads();                 // buf[cur] ready (compiler drains vmcnt)
        if (it < 7) { STAGE(cur ^ 1, (it + 1) * 64) }   // prefetch during MFMA
        #pragma unroll
        for (int ks = 0; ks < 2; ++ks) {
            shortx8 af[2], bf[4];
            #pragma unroll
            for (int i = 0; i < 2; ++i)
                af[i] = *(const shortx8*)&Al[cur][(wm * 32 + i * 16 + l15) * 64 + ks * 32 + quad * 8];
            #pragma unroll
            for (int j = 0; j < 4; ++j)
                bf[j] = *(const shortx8*)&Bl[cur][(wj * 64 + j * 16 + l15) * 64 + ks * 32 + quad * 8];
            #pragma unroll
            for (int i = 0; i < 2; ++i)
                #pragma unroll
                for (int j = 0; j < 4; ++j)
                    acc[i][j] = __builtin_amdgcn_mfma_f32_16x16x32_bf16(af[i], bf[j], acc[i][j], 0, 0, 0);
        }
        cur ^= 1;
    }
    #undef STAGE

    // C/D: col(jloc) = wj*64 + jj*16 + l15, row(m) = mt*64 + wm*32 + i*16 + quad*4 + reg
    if (jt < 32) {
        #pragma unroll
        for (int i = 0; i < 2; ++i)
            #pragma unroll
            for (int jj = 0; jj < 4; ++jj) {
                const int d_   = (jj & 1) * 16 + l15;      // jloc & 31
                const int tloc = wj * 2 + (jj >> 1);       // jloc >> 5
                const int t_   = jt * 4 + tloc;
                #pragma unroll
                for (int reg = 0; reg < 4; ++reg) {
                    const int m_ = mt * 64 + wm * 32 + i * 16 + quad * 4 + reg;
                    ut[(((size_t)bi * 256 + m_) * 128 + t_) * 32 + d_] = f2b(acc[i][jj][reg]);
                }
            }
    } else {
        #pragma unroll
        for (int i = 0; i < 2; ++i)
            #pragma unroll
            for (int jj = 0; jj < 4; ++jj) {
                const int t_ = wj * 64 + jj * 16 + l15;
                #pragma unroll
                for (int reg = 0; reg < 4; ++reg) {
                    const int m_ = mt * 64 + wm * 32 + i * 16 + quad * 4 + reg;
                    sbuf[((size_t)bi * 256 + m_) * 128 + t_] = f2b(acc[i][jj][reg]);
                }
            }
    }
}

// ---------- MFMA MLP: y = relu(bias + Wsum@ftT + r0*(W2@u0T) + r1*(W3@u1T)) ----------
// grid (256, 2). ft transposed in-LDS; W fragments built in-register.
__launch_bounds__(256)
__global__ void k_mlp(const float* __restrict__ ft, const unsigned short* __restrict__ ut,
                      const unsigned short* __restrict__ sbuf, const float* __restrict__ W,
                      const float* __restrict__ bias, float* __restrict__ y) {
    const int m = blockIdx.x, b = blockIdx.y;
    const int tid = threadIdx.x;
    const int wave = tid >> 6, lane = tid & 63;
    const int l15 = lane & 15, quad = lane >> 4;

    __shared__ unsigned short ftt[128 * 32];   // [t][d] bf16, 8 KB

    // stage ft: thread owns d = tid>>3, t-range (tid&7)*16..+15; scatter to [t][d]
    {
        const int d = tid >> 3, t0 = (tid & 7) * 16;
        const float* src = ft + ((size_t)(b * 256 + m) * 32 + d) * 128 + t0;
        float4 v0 = *(const float4*)(src);
        float4 v1 = *(const float4*)(src + 4);
        float4 v2 = *(const float4*)(src + 8);
        float4 v3 = *(const float4*)(src + 12);
        float fv[16] = { v0.x, v0.y, v0.z, v0.w, v1.x, v1.y, v1.z, v1.w,
                         v2.x, v2.y, v2.z, v2.w, v3.x, v3.y, v3.z, v3.w };
        #pragma unroll
        for (int i = 0; i < 16; ++i) ftt[(t0 + i) * 32 + d] = f2b(fv[i]);
    }

    // W fragments in-register: A[m=o][k=d], o = wave*16+l15, d = quad*8..+7
    const int o_ = wave * 16 + l15;
    shortx8 aw, a2, a3;
    {
        const float* wp = W + (size_t)o_ * 96 + quad * 8;
        float4 p0 = *(const float4*)(wp),      p1 = *(const float4*)(wp + 4);
        float4 q0 = *(const float4*)(wp + 32), q1 = *(const float4*)(wp + 36);
        float4 r0_ = *(const float4*)(wp + 64), r1_ = *(const float4*)(wp + 68);
        float w1[8] = { p0.x, p0.y, p0.z, p0.w, p1.x, p1.y, p1.z, p1.w };
        float w2[8] = { q0.x, q0.y, q0.z, q0.w, q1.x, q1.y, q1.z, q1.w };
        float w3[8] = { r0_.x, r0_.y, r0_.z, r0_.w, r1_.x, r1_.y, r1_.z, r1_.w };
        #pragma unroll
        for (int j = 0; j < 8; ++j) {
            aw[j] = (short)f2b(w1[j] + w2[j] + w3[j]);
            a2[j] = (short)f2b(w2[j]);
            a3[j] = (short)f2b(w3[j]);
        }
    }
    float bv[4];
    #pragma unroll
    for (int r = 0; r < 4; ++r) bv[r] = bias[wave * 16 + quad * 4 + r];

    const unsigned short* u0 = ut + ((size_t)((2 * b + 0) * 256 + m) * 128) * 32;
    const unsigned short* u1 = ut + ((size_t)((2 * b + 1) * 256 + m) * 128) * 32;
    const unsigned short* s0 = sbuf + ((size_t)(2 * b + 0) * 256 + m) * 128;
    const unsigned short* s1 = sbuf + ((size_t)(2 * b + 1) * 256 + m) * 128;
    float* yp = y + ((size_t)(b * 256 + m) * 64) * 128;

    __syncthreads();

    #pragma unroll
    for (int tt = 0; tt < 8; ++tt) {
        const int t = tt * 16 + l15;
        shortx8 bf = *(const shortx8*)&ftt[t * 32 + quad * 8];
        shortx8 b0 = *(const shortx8*)(u0 + (size_t)t * 32 + quad * 8);
        shortx8 b1 = *(const shortx8*)(u1 + (size_t)t * 32 + quad * 8);
        floatx4 z = {0.f, 0.f, 0.f, 0.f};
        floatx4 cw = __builtin_amdgcn_mfma_f32_16x16x32_bf16(aw, bf, z, 0, 0, 0);
        floatx4 c2 = __builtin_amdgcn_mfma_f32_16x16x32_bf16(a2, b0, z, 0, 0, 0);
        floatx4 c3 = __builtin_amdgcn_mfma_f32_16x16x32_bf16(a3, b1, z, 0, 0, 0);
        float r0 = 1.f / (b2f(s0[t]) + 1.f);
        float r1 = 1.f / (b2f(s1[t]) + 1.f);
        #pragma unroll
        for (int r = 0; r < 4; ++r) {
            const int o = wave * 16 + quad * 4 + r;
            float v = cw[r] + r0 * c2[r] + r1 * c3[r] + bv[r];
            yp[(size_t)o * 128 + t] = v > 0.f ? v : 0.f;
        }
    }
}

extern "C" void kernel_launch(void* const* d_in, const int* in_sizes, int n_in,
                              void* d_out, int out_size, void* d_ws, size_t ws_size,
                              hipStream_t stream) {
    const float* fc   = (const float*)d_in[0]; // [2,512,32,128]
    const float* ft   = (const float*)d_in[1]; // [2,256,32,128]
    const float* adj  = (const float*)d_in[2]; // [2,2,256,512]
    const float* mask = (const float*)d_in[3]; // [2,128,512]
    const float* W    = (const float*)d_in[4]; // [64,96]
    const float* bias = (const float*)d_in[5]; // [64]
    float* y = (float*)d_out;                  // [2,256,64,128]

    unsigned short* gt   = (unsigned short*)d_ws;            // [2][4224][512]
    unsigned short* adjb = gt   + (size_t)2 * 4224 * 512;    // [4][256][512]
    unsigned short* ut   = adjb + (size_t)4 * 256 * 512;     // [4][256][128][32]
    unsigned short* sbuf = ut   + (size_t)4 * 256 * 128 * 32;// [4][256][128]
    // total ~18.5 MB

    k_prep<<<4736, 256, 0, stream>>>(fc, mask, adj, gt, adjb);
    k_gemm<<<dim3(33, 4, 4), 256, 0, stream>>>(adjb, gt, ut, sbuf);
    k_mlp <<<dim3(256, 2), 256, 0, stream>>>(ft, ut, sbuf, W, bias, y);
}

// Round 9
// 108.574 us; speedup vs baseline: 1.3948x; 1.0050x over previous
//
#include <hip/hip_runtime.h>
#include <cstdint>
#include <cstddef>

// Shapes: b=2, n=512, m=256, d=32, t=128, ORDER=2, C_OUT=64. All I/O fp32.
// Pipeline:
//   k_prep: (a) gt[b][j][n] = bf16(fc[b][n][j]*(1-mask[b][t][n])), j=d*128+t<4096;
//               gt[b][4096+t][n] = bf16(1-mask[b][t][n])   (s-channels)
//           (b) adj fp32->bf16
//   k_gemm: MFMA 64x128 tile, BK=64, double-buffered LDS, 3 blocks/CU.
//           jt<32: tile owns t0=jt*4..+3 x all 32 d -> ut[bi][m][t][d]
//           jt==32: s[bi][m][t]. One block owns each 64B output line.
//   k_mlp : y = relu(bias + Wsum@ftT + r0*(W2@u0T) + r1*(W3@u1T)), r=1/(s+1).
//           grid (m, b, t-half): 4 blocks/CU for latency hiding.

using shortx8 = __attribute__((ext_vector_type(8))) short;
using floatx4 = __attribute__((ext_vector_type(4))) float;

__device__ __forceinline__ float b2f(unsigned short u) {
    union { unsigned int i; float f; } v; v.i = ((unsigned int)u) << 16; return v.f;
}
__device__ __forceinline__ unsigned short f2b(float f) {
    union { float f; unsigned int i; } v; v.f = f;
    unsigned int x = v.i;
    return (unsigned short)((x + 0x7FFFu + ((x >> 16) & 1u)) >> 16); // RNE
}
__device__ __forceinline__ void gl_lds16(const unsigned short* g, unsigned short* l) {
    __builtin_amdgcn_global_load_lds(
        (const __attribute__((address_space(1))) unsigned int*)g,
        (__attribute__((address_space(3))) unsigned int*)l, 16, 0, 0);
}

// ---------- fused prep: gt build [0,4224) + adj->bf16 [4224,4736) ----------
__global__ void k_prep(const float* __restrict__ fc, const float* __restrict__ mask,
                       const float* __restrict__ adj,
                       unsigned short* __restrict__ gt, unsigned short* __restrict__ adjb) {
    const int tid = threadIdx.x;
    __shared__ float wls[32][33];
    __shared__ unsigned short tls[32][34];

    if (blockIdx.x < 4224) {  // ---- gt ----
        const int r_ = blockIdx.x;
        const int jb = r_ % 132;
        const int rem = r_ / 132;
        const int nb = rem & 15, b = rem >> 4;
        const int n0 = nb * 32;
        const int r = tid >> 3, c4 = (tid & 7) * 4;
        if (jb >= 128) {
            const int t0 = (jb - 128) * 32;
            float4 mv = *(const float4*)(mask + ((size_t)b * 128 + t0 + r) * 512 + n0 + c4);
            ushort4 o;
            o.x = f2b(1.f - mv.x); o.y = f2b(1.f - mv.y);
            o.z = f2b(1.f - mv.z); o.w = f2b(1.f - mv.w);
            *(ushort4*)(gt + ((size_t)b * 4224 + 4096 + t0 + r) * 512 + n0 + c4) = o;
            return;
        }
        const int j0 = jb * 32;
        const int t0 = j0 & 127;
        {
            float4 mv = *(const float4*)(mask + ((size_t)b * 128 + t0 + r) * 512 + n0 + c4);
            wls[r][c4 + 0] = 1.f - mv.x; wls[r][c4 + 1] = 1.f - mv.y;
            wls[r][c4 + 2] = 1.f - mv.z; wls[r][c4 + 3] = 1.f - mv.w;
        }
        float4 fv = *(const float4*)(fc + ((size_t)b * 512 + n0 + r) * 4096 + j0 + c4);
        __syncthreads();
        tls[c4 + 0][r] = f2b(fv.x * wls[c4 + 0][r]);
        tls[c4 + 1][r] = f2b(fv.y * wls[c4 + 1][r]);
        tls[c4 + 2][r] = f2b(fv.z * wls[c4 + 2][r]);
        tls[c4 + 3][r] = f2b(fv.w * wls[c4 + 3][r]);
        __syncthreads();
        ushort4 o;
        o.x = tls[r][c4 + 0]; o.y = tls[r][c4 + 1];
        o.z = tls[r][c4 + 2]; o.w = tls[r][c4 + 3];
        *(ushort4*)(gt + ((size_t)b * 4224 + j0 + r) * 512 + n0 + c4) = o;
    } else {  // ---- adj ----
        int i4 = ((blockIdx.x - 4224) * 256 + tid) * 4;
        float4 v = *(const float4*)(adj + i4);
        ushort4 o;
        o.x = f2b(v.x); o.y = f2b(v.y); o.z = f2b(v.z); o.w = f2b(v.w);
        *(ushort4*)(adjb + i4) = o;
    }
}

// ---------- MFMA GEMM, 64x128 tile, BK=64, double-buffered, 3 blocks/CU ----------
// grid (33, 4, 4): jt, mt (64-wide m), bi. 4 waves; wave (w&1)=m-half, (w>>1)=j-half.
__launch_bounds__(256, 3)
__global__ void k_gemm(const unsigned short* __restrict__ adjb,
                       const unsigned short* __restrict__ gt,
                       unsigned short* __restrict__ ut,
                       unsigned short* __restrict__ sbuf) {
    const int jt = blockIdx.x, mt = blockIdx.y, bi = blockIdx.z;
    const int b = bi >> 1;
    const int tid = threadIdx.x;
    const int wave = tid >> 6, lane = tid & 63;
    const int l15 = lane & 15, quad = lane >> 4;
    const int wm = wave & 1, wj = wave >> 1;

    __shared__ __align__(16) unsigned short Al[2][64 * 64];   // 2 x 8 KB
    __shared__ __align__(16) unsigned short Bl[2][128 * 64];  // 2 x 16 KB

    const int srow = lane >> 3;          // 0..7 row within 8-row chunk
    const int skq  = (lane & 7) * 8;     // 0..56 k-slot (8 shorts)
    const unsigned short* Ag = adjb + ((size_t)bi * 256 + mt * 64) * 512;
    const unsigned short* Bgb = gt + (size_t)b * 4224 * 512;

    // B row map: tile-local row r -> gt row j
    //   jt<32 : j = (r&31)*128 + jt*4 + (r>>5)     jt==32: j = 4096 + r
    #define STAGE(buf, k0)                                                        \
        _Pragma("unroll")                                                         \
        for (int rr = 0; rr < 2; ++rr) {                                          \
            const int ch = wave * 2 + rr;        /* A chunks 0..7 */              \
            const int row = ch * 8 + srow;                                        \
            gl_lds16(Ag + (size_t)row * 512 + (k0) + skq, &Al[buf][ch * 512]);    \
        }                                                                         \
        _Pragma("unroll")                                                         \
        for (int rr = 0; rr < 4; ++rr) {                                          \
            const int ch = wave * 4 + rr;        /* B chunks 0..15 */             \
            const int row = ch * 8 + srow;                                        \
            const int jrow = (jt < 32) ? ((row & 31) * 128 + jt * 4 + (row >> 5)) \
                                       : (4096 + row);                            \
            gl_lds16(Bgb + (size_t)jrow * 512 + (k0) + skq, &Bl[buf][ch * 512]);  \
        }

    floatx4 acc[2][4];
    #pragma unroll
    for (int i = 0; i < 2; ++i)
        #pragma unroll
        for (int j = 0; j < 4; ++j) acc[i][j] = (floatx4){0.f, 0.f, 0.f, 0.f};

    STAGE(0, 0)
    int cur = 0;
    for (int it = 0; it < 8; ++it) {
        __syncthreads();                 // buf[cur] ready (compiler drains vmcnt)
        if (it < 7) { STAGE(cur ^ 1, (it + 1) * 64) }   // prefetch during MFMA
        #pragma unroll
        for (int ks = 0; ks < 2; ++ks) {
            shortx8 af[2], bf[4];
            #pragma unroll
            for (int i = 0; i < 2; ++i)
                af[i] = *(const shortx8*)&Al[cur][(wm * 32 + i * 16 + l15) * 64 + ks * 32 + quad * 8];
            #pragma unroll
            for (int j = 0; j < 4; ++j)
                bf[j] = *(const shortx8*)&Bl[cur][(wj * 64 + j * 16 + l15) * 64 + ks * 32 + quad * 8];
            #pragma unroll
            for (int i = 0; i < 2; ++i)
                #pragma unroll
                for (int j = 0; j < 4; ++j)
                    acc[i][j] = __builtin_amdgcn_mfma_f32_16x16x32_bf16(af[i], bf[j], acc[i][j], 0, 0, 0);
        }
        cur ^= 1;
    }
    #undef STAGE

    // C/D: col(jloc) = wj*64 + jj*16 + l15, row(m) = mt*64 + wm*32 + i*16 + quad*4 + reg
    if (jt < 32) {
        #pragma unroll
        for (int i = 0; i < 2; ++i)
            #pragma unroll
            for (int jj = 0; jj < 4; ++jj) {
                const int d_   = (jj & 1) * 16 + l15;      // jloc & 31
                const int tloc = wj * 2 + (jj >> 1);       // jloc >> 5
                const int t_   = jt * 4 + tloc;
                #pragma unroll
                for (int reg = 0; reg < 4; ++reg) {
                    const int m_ = mt * 64 + wm * 32 + i * 16 + quad * 4 + reg;
                    ut[(((size_t)bi * 256 + m_) * 128 + t_) * 32 + d_] = f2b(acc[i][jj][reg]);
                }
            }
    } else {
        #pragma unroll
        for (int i = 0; i < 2; ++i)
            #pragma unroll
            for (int jj = 0; jj < 4; ++jj) {
                const int t_ = wj * 64 + jj * 16 + l15;
                #pragma unroll
                for (int reg = 0; reg < 4; ++reg) {
                    const int m_ = mt * 64 + wm * 32 + i * 16 + quad * 4 + reg;
                    sbuf[((size_t)bi * 256 + m_) * 128 + t_] = f2b(acc[i][jj][reg]);
                }
            }
    }
}

// ---------- MFMA MLP: y = relu(bias + Wsum@ftT + r0*(W2@u0T) + r1*(W3@u1T)) ----------
// grid (256, 2, 2): m, b, t-half (64 t each). 4 blocks/CU.
__launch_bounds__(256)
__global__ void k_mlp(const float* __restrict__ ft, const unsigned short* __restrict__ ut,
                      const unsigned short* __restrict__ sbuf, const float* __restrict__ W,
                      const float* __restrict__ bias, float* __restrict__ y) {
    const int m = blockIdx.x, b = blockIdx.y, tz = blockIdx.z;
    const int tbase = tz * 64;
    const int tid = threadIdx.x;
    const int wave = tid >> 6, lane = tid & 63;
    const int l15 = lane & 15, quad = lane >> 4;

    __shared__ unsigned short ftt[64 * 32];   // [t-local][d] bf16, 4 KB

    // stage ft: thread owns d = tid>>3, t-range tbase + (tid&7)*8 .. +7
    {
        const int d = tid >> 3, t0 = (tid & 7) * 8;
        const float* src = ft + ((size_t)(b * 256 + m) * 32 + d) * 128 + tbase + t0;
        float4 v0 = *(const float4*)(src);
        float4 v1 = *(const float4*)(src + 4);
        float fv[8] = { v0.x, v0.y, v0.z, v0.w, v1.x, v1.y, v1.z, v1.w };
        #pragma unroll
        for (int i = 0; i < 8; ++i) ftt[(t0 + i) * 32 + d] = f2b(fv[i]);
    }

    // W fragments in-register: A[m=o][k=d], o = wave*16+l15, d = quad*8..+7
    const int o_ = wave * 16 + l15;
    shortx8 aw, a2, a3;
    {
        const float* wp = W + (size_t)o_ * 96 + quad * 8;
        float4 p0 = *(const float4*)(wp),      p1 = *(const float4*)(wp + 4);
        float4 q0 = *(const float4*)(wp + 32), q1 = *(const float4*)(wp + 36);
        float4 r0_ = *(const float4*)(wp + 64), r1_ = *(const float4*)(wp + 68);
        float w1[8] = { p0.x, p0.y, p0.z, p0.w, p1.x, p1.y, p1.z, p1.w };
        float w2[8] = { q0.x, q0.y, q0.z, q0.w, q1.x, q1.y, q1.z, q1.w };
        float w3[8] = { r0_.x, r0_.y, r0_.z, r0_.w, r1_.x, r1_.y, r1_.z, r1_.w };
        #pragma unroll
        for (int j = 0; j < 8; ++j) {
            aw[j] = (short)f2b(w1[j] + w2[j] + w3[j]);
            a2[j] = (short)f2b(w2[j]);
            a3[j] = (short)f2b(w3[j]);
        }
    }
    float bv[4];
    #pragma unroll
    for (int r = 0; r < 4; ++r) bv[r] = bias[wave * 16 + quad * 4 + r];

    const unsigned short* u0 = ut + ((size_t)((2 * b + 0) * 256 + m) * 128 + tbase) * 32;
    const unsigned short* u1 = ut + ((size_t)((2 * b + 1) * 256 + m) * 128 + tbase) * 32;
    const unsigned short* s0 = sbuf + ((size_t)(2 * b + 0) * 256 + m) * 128 + tbase;
    const unsigned short* s1 = sbuf + ((size_t)(2 * b + 1) * 256 + m) * 128 + tbase;
    float* yp = y + ((size_t)(b * 256 + m) * 64) * 128 + tbase;

    __syncthreads();

    #pragma unroll
    for (int tt = 0; tt < 4; ++tt) {
        const int t = tt * 16 + l15;      // t-local in [0,64)
        shortx8 bf = *(const shortx8*)&ftt[t * 32 + quad * 8];
        shortx8 b0 = *(const shortx8*)(u0 + (size_t)t * 32 + quad * 8);
        shortx8 b1 = *(const shortx8*)(u1 + (size_t)t * 32 + quad * 8);
        floatx4 z = {0.f, 0.f, 0.f, 0.f};
        floatx4 cw = __builtin_amdgcn_mfma_f32_16x16x32_bf16(aw, bf, z, 0, 0, 0);
        floatx4 c2 = __builtin_amdgcn_mfma_f32_16x16x32_bf16(a2, b0, z, 0, 0, 0);
        floatx4 c3 = __builtin_amdgcn_mfma_f32_16x16x32_bf16(a3, b1, z, 0, 0, 0);
        float r0 = 1.f / (b2f(s0[t]) + 1.f);
        float r1 = 1.f / (b2f(s1[t]) + 1.f);
        #pragma unroll
        for (int r = 0; r < 4; ++r) {
            const int o = wave * 16 + quad * 4 + r;
            float v = cw[r] + r0 * c2[r] + r1 * c3[r] + bv[r];
            yp[(size_t)o * 128 + t] = v > 0.f ? v : 0.f;
        }
    }
}

extern "C" void kernel_launch(void* const* d_in, const int* in_sizes, int n_in,
                              void* d_out, int out_size, void* d_ws, size_t ws_size,
                              hipStream_t stream) {
    const float* fc   = (const float*)d_in[0]; // [2,512,32,128]
    const float* ft   = (const float*)d_in[1]; // [2,256,32,128]
    const float* adj  = (const float*)d_in[2]; // [2,2,256,512]
    const float* mask = (const float*)d_in[3]; // [2,128,512]
    const float* W    = (const float*)d_in[4]; // [64,96]
    const float* bias = (const float*)d_in[5]; // [64]
    float* y = (float*)d_out;                  // [2,256,64,128]

    unsigned short* gt   = (unsigned short*)d_ws;            // [2][4224][512]
    unsigned short* adjb = gt   + (size_t)2 * 4224 * 512;    // [4][256][512]
    unsigned short* ut   = adjb + (size_t)4 * 256 * 512;     // [4][256][128][32]
    unsigned short* sbuf = ut   + (size_t)4 * 256 * 128 * 32;// [4][256][128]
    // total ~18.5 MB

    k_prep<<<4736, 256, 0, stream>>>(fc, mask, adj, gt, adjb);
    k_gemm<<<dim3(33, 4, 4), 256, 0, stream>>>(adjb, gt, ut, sbuf);
    k_mlp <<<dim3(256, 2, 2), 256, 0, stream>>>(ft, ut, sbuf, W, bias, y);
}